// Round 9
// baseline (395.054 us; speedup 1.0000x reference)
//
#include <hip/hip_runtime.h>
#include <hip/hip_bf16.h>

#define S_LEN 2048
#define NH    32
#define NKV   8
#define HD    128
#define QBLK  128
#define KVBLK 64
#define NWAVE 8
#define KST   136   // K_lds row stride bf16 (68 dwords ≡ 4 mod 32 -> 2-way b128 reads, free)
#define VST   68    // Vt col stride bf16 (34 dwords ≡ 2 mod 32 -> 2-way writes/reads, free)
#define PST   72    // P_lds row stride bf16 (36 dwords -> 2-way in-phase, free)

typedef __bf16 bf16x8   __attribute__((ext_vector_type(8)));
typedef __bf16 bf16x4_t __attribute__((ext_vector_type(4)));
typedef float  f32x4    __attribute__((ext_vector_type(4)));

// (512, 4): 4 waves/EU min -> VGPR cap 128 (no spills for ~100-reg live set),
// still 2 blocks/CU (LDS-limited anyway). Bare (512) made the compiler target
// 8 waves/EU -> 64 VGPRs -> catastrophic scratch spills in the KV loop (r8).
__global__ __launch_bounds__(512, 4)
void sdpa_fwd(const float* __restrict__ Q, const float* __restrict__ K,
              const float* __restrict__ V, float* __restrict__ O)
{
    __shared__ __align__(16) unsigned short Klds_u[KVBLK * KST];   // 17408 B
    __shared__ __align__(16) unsigned short Vt_u[HD * VST];        // 17408 B
    __shared__ __align__(16) unsigned short P_u[QBLK * PST];       // 18432 B
    __bf16* Klds = (__bf16*)Klds_u;
    __bf16* Vt   = (__bf16*)Vt_u;
    __bf16* Pl   = (__bf16*)P_u;

    const int qt   = (int)gridDim.x - 1 - (int)blockIdx.x;  // heavy tiles first
    const int h    = blockIdx.y;
    const int hkv  = h >> 2;            // GQA: 4 query heads per kv head
    const int q0   = qt * QBLK;
    const int tid  = threadIdx.x;
    const int wv   = tid >> 6;          // wave 0..7, owns q rows q0+16*wv..+15
    const int lane = tid & 63;
    const int lr   = lane & 15;
    const int lg   = lane >> 4;
    const int qrow0 = q0 + wv * 16;

    const float NEG_INF = -__builtin_inff();
    const float QSCALE  = (float)(0.08838834764831845 * 1.4426950408889634); // scale*log2e

    // ---- Q fragments (A operand): row=lr (local), k = f*32 + lg*8 + j ----
    bf16x8 qf[4];
    {
        const float* qp = Q + (size_t)(qrow0 + lr) * (NH * HD) + h * HD + lg * 8;
        #pragma unroll
        for (int f = 0; f < 4; ++f) {
            float4 a = *(const float4*)(qp + f * 32);
            float4 b = *(const float4*)(qp + f * 32 + 4);
            bf16x8 t;
            t[0] = (__bf16)(a.x * QSCALE); t[1] = (__bf16)(a.y * QSCALE);
            t[2] = (__bf16)(a.z * QSCALE); t[3] = (__bf16)(a.w * QSCALE);
            t[4] = (__bf16)(b.x * QSCALE); t[5] = (__bf16)(b.y * QSCALE);
            t[6] = (__bf16)(b.z * QSCALE); t[7] = (__bf16)(b.w * QSCALE);
            qf[f] = t;
        }
    }

    f32x4 o[8];
    #pragma unroll
    for (int dt = 0; dt < 8; ++dt) o[dt] = (f32x4){0.f, 0.f, 0.f, 0.f};
    float m_r[4] = {NEG_INF, NEG_INF, NEG_INF, NEG_INF};
    float l_r[4] = {0.f, 0.f, 0.f, 0.f};

    const int kb_end = q0 + QBLK - KVBLK;   // last kv tile any row of this block needs
    for (int kb = 0; kb <= kb_end; kb += KVBLK) {
        __syncthreads();   // previous tile's compute done before overwriting LDS
        // ---- stage K [64][128] -> Klds bf16 (coalesced float4, b64 LDS writes) ----
        #pragma unroll
        for (int it = 0; it < 4; ++it) {
            int idx = (it * 512 + tid) * 4;     // float index in 64x128 tile
            int row = idx >> 7, col = idx & 127;
            float4 k4 = *(const float4*)(K + (size_t)(kb + row) * (NKV * HD) + hkv * HD + col);
            bf16x4_t kb4;
            kb4[0] = (__bf16)k4.x; kb4[1] = (__bf16)k4.y;
            kb4[2] = (__bf16)k4.z; kb4[3] = (__bf16)k4.w;
            *(bf16x4_t*)&Klds[row * KST + col] = kb4;
        }
        // ---- stage V transposed: read 4 rows x 1 col (coalesced per row), b64 write ----
        #pragma unroll
        for (int it = 0; it < 4; ++it) {
            int task = it * 512 + tid;          // 0..2047 = 128 cols x 16 row-groups
            int col = task & 127, rg = task >> 7;
            const float* vp = V + (size_t)(kb + rg * 4) * (NKV * HD) + hkv * HD + col;
            bf16x4_t vb;
            vb[0] = (__bf16)vp[0];
            vb[1] = (__bf16)vp[NKV * HD];
            vb[2] = (__bf16)vp[2 * NKV * HD];
            vb[3] = (__bf16)vp[3 * NKV * HD];
            *(bf16x4_t*)&Vt[col * VST + rg * 4] = vb;
        }
        __syncthreads();

        if (kb > qrow0 + 15) continue;   // wave-uniform: no valid keys for this wave's rows

        // ---- QK^T: 4 key-tiles of 16, each 4 MFMAs over D=128 ----
        f32x4 s[4];
        #pragma unroll
        for (int t = 0; t < 4; ++t) {
            f32x4 acc = (f32x4){0.f, 0.f, 0.f, 0.f};
            #pragma unroll
            for (int f = 0; f < 4; ++f) {
                bf16x8 kf = *(bf16x8*)&Klds[(t * 16 + lr) * KST + f * 32 + lg * 8];
                acc = __builtin_amdgcn_mfma_f32_16x16x32_bf16(qf[f], kf, acc, 0, 0, 0);
            }
            s[t] = acc;
        }

        // ---- causal mask (partial tiles only) + online softmax ----
        const bool needmask = (kb + KVBLK - 1 > qrow0);
        float sv[4][4];
        float mt[4] = {NEG_INF, NEG_INF, NEG_INF, NEG_INF};
        #pragma unroll
        for (int t = 0; t < 4; ++t)
            #pragma unroll
            for (int r = 0; r < 4; ++r) {
                float val = s[t][r];
                if (needmask && (kb + t * 16 + lr) > (qrow0 + lg * 4 + r)) val = NEG_INF;
                sv[t][r] = val;
                mt[r] = fmaxf(mt[r], val);
            }
        #pragma unroll
        for (int r = 0; r < 4; ++r) {
            #pragma unroll
            for (int off = 1; off < 16; off <<= 1)
                mt[r] = fmaxf(mt[r], __shfl_xor(mt[r], off));
        }
        float alpha[4];
        #pragma unroll
        for (int r = 0; r < 4; ++r) {
            float mn  = fmaxf(m_r[r], mt[r]);
            alpha[r]  = __builtin_amdgcn_exp2f(m_r[r] - mn);
            m_r[r]    = mn;
            l_r[r]   *= alpha[r];
        }
        #pragma unroll
        for (int dt = 0; dt < 8; ++dt) {
            o[dt][0] *= alpha[0]; o[dt][1] *= alpha[1];
            o[dt][2] *= alpha[2]; o[dt][3] *= alpha[3];
        }
        // ---- P = exp2(s - m), bf16, transposed through per-wave LDS slab ----
        #pragma unroll
        for (int t = 0; t < 4; ++t)
            #pragma unroll
            for (int r = 0; r < 4; ++r) {
                float p = __builtin_amdgcn_exp2f(sv[t][r] - m_r[r]);
                l_r[r] += p;
                Pl[(wv * 16 + lg * 4 + r) * PST + t * 16 + lr] = (__bf16)p;
            }
        // ---- PV: O += P * V ----
        #pragma unroll
        for (int ks = 0; ks < 2; ++ks) {
            bf16x8 pf = *(bf16x8*)&Pl[(wv * 16 + lr) * PST + ks * 32 + lg * 8];
            #pragma unroll
            for (int dt = 0; dt < 8; ++dt) {
                bf16x8 vf = *(bf16x8*)&Vt[(dt * 16 + lr) * VST + ks * 32 + lg * 8];
                o[dt] = __builtin_amdgcn_mfma_f32_16x16x32_bf16(pf, vf, o[dt], 0, 0, 0);
            }
        }
    }

    // ---- finalize: reduce row-sums across the 16-lane col group, normalize ----
    float inv[4];
    #pragma unroll
    for (int r = 0; r < 4; ++r) {
        float lsum = l_r[r];
        #pragma unroll
        for (int off = 1; off < 16; off <<= 1)
            lsum += __shfl_xor(lsum, off);
        inv[r] = 1.0f / lsum;
    }
    #pragma unroll
    for (int dt = 0; dt < 8; ++dt)
        #pragma unroll
        for (int r = 0; r < 4; ++r) {
            int qrow = qrow0 + lg * 4 + r;
            O[(size_t)qrow * (NH * HD) + h * HD + dt * 16 + lr] = o[dt][r] * inv[r];
        }
}

extern "C" void kernel_launch(void* const* d_in, const int* in_sizes, int n_in,
                              void* d_out, int out_size, void* d_ws, size_t ws_size,
                              hipStream_t stream)
{
    const float* Q = (const float*)d_in[0];
    const float* K = (const float*)d_in[1];
    const float* V = (const float*)d_in[2];
    float* O = (float*)d_out;
    dim3 grid(S_LEN / QBLK, NH);
    sdpa_fwd<<<grid, 512, 0, stream>>>(Q, K, V, O);
}

// Round 10
// 336.347 us; speedup vs baseline: 1.1745x; 1.1745x over previous
//
#include <hip/hip_runtime.h>
#include <hip/hip_bf16.h>

#define S_LEN 2048
#define NH    32
#define NKV   8
#define HD    128
#define KVBLK 64
#define KST   136   // K_lds row stride bf16 (68 dwords ≡ 4 mod 32 -> 2-way b128 reads, free)
#define VST   68    // Vt col stride bf16 (34 dwords ≡ 2 mod 32 -> 2-way writes/reads, free)
#define PST   72    // P_lds row stride bf16 (36 dwords -> 2-way in-phase, free)

typedef __bf16 bf16x8   __attribute__((ext_vector_type(8)));
typedef __bf16 bf16x4_t __attribute__((ext_vector_type(4)));
typedef float  f32x4    __attribute__((ext_vector_type(4)));

// (512,4): VGPR cap 128 — needed for the +32 in-flight staging registers.
// Balance-by-construction: block p pairs q-tiles p and 31-p (33 tile-units const).
__global__ __launch_bounds__(512, 4)
void sdpa_fwd(const float* __restrict__ Q, const float* __restrict__ K,
              const float* __restrict__ V, float* __restrict__ O)
{
    __shared__ __align__(16) unsigned short Klds_u[KVBLK * KST];   // 17408 B
    __shared__ __align__(16) unsigned short Vt_u[HD * VST];        // 17408 B
    __shared__ __align__(16) unsigned short P_u[128 * PST];        // 18432 B
    __bf16* Klds = (__bf16*)Klds_u;
    __bf16* Vt   = (__bf16*)Vt_u;
    __bf16* Pl   = (__bf16*)P_u;

    const int p    = blockIdx.x;        // pair index 0..15
    const int h    = blockIdx.y;
    const int hkv  = h >> 2;            // GQA: 4 query heads per kv head
    const int tid  = threadIdx.x;
    const int wv   = tid >> 6;          // wave 0..7
    const int lane = tid & 63;
    const int lr   = lane & 15;
    const int lg   = lane >> 4;
    // waves 0-3: low tile rows [64p, 64p+64); waves 4-7: high tile [2048-64(p+1), 2048-64p)
    const int qrow0 = (wv < 4) ? (64 * p + 16 * wv)
                               : (S_LEN - 64 * (p + 1) + 16 * (wv - 4));

    const float NEG_INF = -__builtin_inff();
    const float QSCALE  = (float)(0.08838834764831845 * 1.4426950408889634); // scale*log2e

    // ---- Q fragments (A operand): row=lr (local), k = f*32 + lg*8 + j ----
    bf16x8 qf[4];
    {
        const float* qp = Q + (size_t)(qrow0 + lr) * (NH * HD) + h * HD + lg * 8;
        #pragma unroll
        for (int f = 0; f < 4; ++f) {
            float4 a = *(const float4*)(qp + f * 32);
            float4 b = *(const float4*)(qp + f * 32 + 4);
            bf16x8 t;
            t[0] = (__bf16)(a.x * QSCALE); t[1] = (__bf16)(a.y * QSCALE);
            t[2] = (__bf16)(a.z * QSCALE); t[3] = (__bf16)(a.w * QSCALE);
            t[4] = (__bf16)(b.x * QSCALE); t[5] = (__bf16)(b.y * QSCALE);
            t[6] = (__bf16)(b.z * QSCALE); t[7] = (__bf16)(b.w * QSCALE);
            qf[f] = t;
        }
    }

    f32x4 o[8];
    #pragma unroll
    for (int dt = 0; dt < 8; ++dt) o[dt] = (f32x4){0.f, 0.f, 0.f, 0.f};
    float m_r[4] = {NEG_INF, NEG_INF, NEG_INF, NEG_INF};
    float l_r[4] = {0.f, 0.f, 0.f, 0.f};

    // ---- async staging state (in-flight registers for next tile) ----
    float4 kreg[4];
    float  vreg[16];

    auto issue_loads = [&](int kb) {
        #pragma unroll
        for (int it = 0; it < 4; ++it) {
            int idx = (it * 512 + tid) * 4;     // float index in 64x128 K tile
            int row = idx >> 7, col = idx & 127;
            kreg[it] = *(const float4*)(K + (size_t)(kb + row) * (NKV * HD) + hkv * HD + col);
        }
        #pragma unroll
        for (int it = 0; it < 4; ++it) {
            int task = it * 512 + tid;          // 128 cols x 16 row-groups
            int col = task & 127, rg = task >> 7;
            const float* vp = V + (size_t)(kb + rg * 4) * (NKV * HD) + hkv * HD + col;
            vreg[it * 4 + 0] = vp[0];
            vreg[it * 4 + 1] = vp[NKV * HD];
            vreg[it * 4 + 2] = vp[2 * NKV * HD];
            vreg[it * 4 + 3] = vp[3 * NKV * HD];
        }
    };
    auto write_lds = [&]() {
        #pragma unroll
        for (int it = 0; it < 4; ++it) {
            int idx = (it * 512 + tid) * 4;
            int row = idx >> 7, col = idx & 127;
            bf16x4_t kb4;
            kb4[0] = (__bf16)kreg[it].x; kb4[1] = (__bf16)kreg[it].y;
            kb4[2] = (__bf16)kreg[it].z; kb4[3] = (__bf16)kreg[it].w;
            *(bf16x4_t*)&Klds[row * KST + col] = kb4;
        }
        #pragma unroll
        for (int it = 0; it < 4; ++it) {
            int task = it * 512 + tid;
            int col = task & 127, rg = task >> 7;
            bf16x4_t vb;
            vb[0] = (__bf16)vreg[it * 4 + 0]; vb[1] = (__bf16)vreg[it * 4 + 1];
            vb[2] = (__bf16)vreg[it * 4 + 2]; vb[3] = (__bf16)vreg[it * 4 + 3];
            *(bf16x4_t*)&Vt[col * VST + rg * 4] = vb;
        }
    };

    const int kb_end = S_LEN - KVBLK * (p + 1);   // high tile's last kv tile
    issue_loads(0);
    write_lds();

    for (int kb = 0; kb <= kb_end; kb += KVBLK) {
        __syncthreads();   // staged tile kb visible to all waves
        const bool havenext = (kb + KVBLK <= kb_end);
        if (havenext) issue_loads(kb + KVBLK);   // HBM latency hides under compute

        if (kb <= qrow0 + 15) {   // wave-uniform: this wave has valid keys in tile kb
            // ---- QK^T: 4 key-tiles of 16, each 4 MFMAs over D=128 ----
            f32x4 s[4];
            #pragma unroll
            for (int t = 0; t < 4; ++t) {
                f32x4 acc = (f32x4){0.f, 0.f, 0.f, 0.f};
                #pragma unroll
                for (int f = 0; f < 4; ++f) {
                    bf16x8 kf = *(bf16x8*)&Klds[(t * 16 + lr) * KST + f * 32 + lg * 8];
                    acc = __builtin_amdgcn_mfma_f32_16x16x32_bf16(qf[f], kf, acc, 0, 0, 0);
                }
                s[t] = acc;
            }

            // ---- causal mask (partial tiles only) + online softmax ----
            const bool needmask = (kb + KVBLK - 1 > qrow0);
            float sv[4][4];
            float mt[4] = {NEG_INF, NEG_INF, NEG_INF, NEG_INF};
            #pragma unroll
            for (int t = 0; t < 4; ++t)
                #pragma unroll
                for (int r = 0; r < 4; ++r) {
                    float val = s[t][r];
                    if (needmask && (kb + t * 16 + lr) > (qrow0 + lg * 4 + r)) val = NEG_INF;
                    sv[t][r] = val;
                    mt[r] = fmaxf(mt[r], val);
                }
            #pragma unroll
            for (int r = 0; r < 4; ++r) {
                #pragma unroll
                for (int off = 1; off < 16; off <<= 1)
                    mt[r] = fmaxf(mt[r], __shfl_xor(mt[r], off));
            }
            float alpha[4];
            #pragma unroll
            for (int r = 0; r < 4; ++r) {
                float mn  = fmaxf(m_r[r], mt[r]);
                alpha[r]  = __builtin_amdgcn_exp2f(m_r[r] - mn);
                m_r[r]    = mn;
                l_r[r]   *= alpha[r];
            }
            #pragma unroll
            for (int dt = 0; dt < 8; ++dt) {
                o[dt][0] *= alpha[0]; o[dt][1] *= alpha[1];
                o[dt][2] *= alpha[2]; o[dt][3] *= alpha[3];
            }
            // ---- P = exp2(s - m), bf16, transposed through per-wave LDS slab ----
            #pragma unroll
            for (int t = 0; t < 4; ++t)
                #pragma unroll
                for (int r = 0; r < 4; ++r) {
                    float pv = __builtin_amdgcn_exp2f(sv[t][r] - m_r[r]);
                    l_r[r] += pv;
                    Pl[(wv * 16 + lg * 4 + r) * PST + t * 16 + lr] = (__bf16)pv;
                }
            // ---- PV: O += P * V ----
            #pragma unroll
            for (int ks = 0; ks < 2; ++ks) {
                bf16x8 pf = *(bf16x8*)&Pl[(wv * 16 + lr) * PST + ks * 32 + lg * 8];
                #pragma unroll
                for (int dt = 0; dt < 8; ++dt) {
                    bf16x8 vf = *(bf16x8*)&Vt[(dt * 16 + lr) * VST + ks * 32 + lg * 8];
                    o[dt] = __builtin_amdgcn_mfma_f32_16x16x32_bf16(pf, vf, o[dt], 0, 0, 0);
                }
            }
        }

        __syncthreads();   // all reads of the staged tile done before overwrite
        if (havenext) write_lds();
    }

    // ---- finalize: reduce row-sums across the 16-lane col group, normalize ----
    float inv[4];
    #pragma unroll
    for (int r = 0; r < 4; ++r) {
        float lsum = l_r[r];
        #pragma unroll
        for (int off = 1; off < 16; off <<= 1)
            lsum += __shfl_xor(lsum, off);
        inv[r] = 1.0f / lsum;
    }
    #pragma unroll
    for (int dt = 0; dt < 8; ++dt)
        #pragma unroll
        for (int r = 0; r < 4; ++r) {
            int qrow = qrow0 + lg * 4 + r;
            O[(size_t)qrow * (NH * HD) + h * HD + dt * 16 + lr] = o[dt][r] * inv[r];
        }
}

extern "C" void kernel_launch(void* const* d_in, const int* in_sizes, int n_in,
                              void* d_out, int out_size, void* d_ws, size_t ws_size,
                              hipStream_t stream)
{
    const float* Q = (const float*)d_in[0];
    const float* K = (const float*)d_in[1];
    const float* V = (const float*)d_in[2];
    float* O = (float*)d_out;
    dim3 grid(S_LEN / 128, NH);   // 16 pair-blocks x 32 heads
    sdpa_fwd<<<grid, 512, 0, stream>>>(Q, K, V, O);
}